// Round 5
// baseline (610.836 us; speedup 1.0000x reference)
//
#include <hip/hip_runtime.h>
#include <hip/hip_fp16.h>
#include <hip/hip_cooperative_groups.h>

namespace cg = cooperative_groups;

// PatchMatch stereo — MI355X (gfx950), fused cooperative version (R4).
// B=1, C=32, H=128, W=256, S=12, FILTER=3, TEMP=7, ITERATIONS=2
// Rounds h,v,h,v fused into ONE kernel, 2 grid.sync()s.
// R4 change: right row staged in LDS as packed half2 (channels 2c,2c+1 per
// 32-bit word) -> LDS 37KB -> 18KB -> 6 blocks/CU co-resident (24 waves/CU,
// was 8). One ds_read2_b32 now feeds 4 fmas. left/noise/softmax stay f32.
// Grid 128 rows x 12 s = 1536 blocks = exactly 6/CU; launch_bounds(256,6)
// caps VGPRs at 85. Checked fallback: 3-kernel split if coop launch rejected.

namespace {
constexpr int C = 32;
constexpr int H = 128;
constexpr int W = 256;
constexpr int S = 12;
constexpr int HW = H * W;
constexpr int C2 = C / 2;             // 16 packed channel-pair rows
constexpr int PP = 264;               // words/row: [0..2]=0, [3]=x=-1(0), [4..259]=x 0..255, [260]=x=256(0), [261..263]=0
constexpr int NPITCH = W + 2;         // LDS noise row: 1 front, 1 back pad
constexpr float TEMP_OVER_C = 7.0f / 32.0f;
constexpr float INTERVAL = 1.0f / (S + 1);
}

__device__ __forceinline__ void eval_sample(
    const unsigned int* __restrict__ sP, const float la[C], int w,
    float imin, float sc, const float np[3], float& ds_out, float& dn_out)
{
    float cost[3], dsamp[3];
    #pragma unroll
    for (int c = 0; c < 3; ++c) {
        const float disp = fmaf(np[c], sc, imin);
        dsamp[c] = disp;
        const float xs = (float)w - disp;
        const float x0f = floorf(xs);
        const float frac = xs - x0f;
        const int x0 = (int)x0f;
        const float v0 = (x0 >= 0 && x0 < W) ? 1.0f : 0.0f;
        const float v1 = (x0 >= -1 && x0 < W - 1) ? 1.0f : 0.0f;
        const int base = x0 < -1 ? -1 : (x0 > W - 1 ? W - 1 : x0);

        const unsigned int* p = &sP[4 + base];
        float d0 = 0.f, d1 = 0.f;
        #pragma unroll
        for (int k = 0; k < C2; ++k) {
            const unsigned int u0 = p[0];
            const unsigned int u1 = p[1];          // -> ds_read2_b32
            const __half2 h0 = *(const __half2*)&u0;   // (ch 2k @ x0, ch 2k+1 @ x0)
            const __half2 h1 = *(const __half2*)&u1;   // same @ x0+1
            d0 = fmaf(la[2 * k],     __low2float(h0),  d0);
            d0 = fmaf(la[2 * k + 1], __high2float(h0), d0);
            d1 = fmaf(la[2 * k],     __low2float(h1),  d1);
            d1 = fmaf(la[2 * k + 1], __high2float(h1), d1);
            p += PP;
        }
        const float w0 = (1.0f - frac) * v0;
        const float w1 = frac * v1;
        cost[c] = (w0 * d0 + w1 * d1) * TEMP_OVER_C;
    }
    const float m = fmaxf(cost[0], fmaxf(cost[1], cost[2]));
    const float e0 = __expf(cost[0] - m);
    const float e1 = __expf(cost[1] - m);
    const float e2 = __expf(cost[2] - m);
    const float inv = 1.0f / (e0 + e1 + e2);
    ds_out = (e0 * dsamp[0] + e1 * dsamp[1] + e2 * dsamp[2]) * inv;
    dn_out = (e0 * np[0] + e1 * np[1] + e2 * np[2]) * inv;
}

// Stage right row (channel-pair packed f16) into sP, left column into la.
__device__ __forceinline__ void stage_block(
    const float* __restrict__ left, const float* __restrict__ right,
    const float* __restrict__ min_disp, const float* __restrict__ max_disp,
    unsigned int* sP, int w, int row, float la[C], float& sc, float& imin, int s)
{
    // zero pads: 8 words per c2-row x 16 rows = 128 -> threads 0..127
    if (w < 128) {
        const int r = w >> 3;
        const int j = w & 7;
        const int idx = (j < 4) ? j : (256 + j);   // 0..3 or 260..263
        sP[r * PP + idx] = 0u;
    }
    // main words x=0..255 at [4..259]: 16 rows x 64 groups of 4 words
    #pragma unroll
    for (int i = 0; i < 4; ++i) {
        const int g = w + 256 * i;                 // group 0..1023
        const int c2 = g >> 6;
        const int x = (g & 63) << 2;
        const float4 a = *(const float4*)&right[(2 * c2)     * HW + row + x];
        const float4 b = *(const float4*)&right[(2 * c2 + 1) * HW + row + x];
        __half2 h0 = __floats2half2_rn(a.x, b.x);
        __half2 h1 = __floats2half2_rn(a.y, b.y);
        __half2 h2 = __floats2half2_rn(a.z, b.z);
        __half2 h3 = __floats2half2_rn(a.w, b.w);
        uint4 pk;
        pk.x = *(unsigned int*)&h0;
        pk.y = *(unsigned int*)&h1;
        pk.z = *(unsigned int*)&h2;
        pk.w = *(unsigned int*)&h3;
        *(uint4*)&sP[c2 * PP + 4 + x] = pk;        // 16B aligned
    }
    #pragma unroll
    for (int c = 0; c < C; ++c)
        la[c] = left[c * HW + row + w];

    const float mind = fmaxf(min_disp[row + w], 0.0f);
    const float maxd = fmaxf(max_disp[row + w], 0.0f);
    sc = (maxd - mind) * INTERVAL;
    imin = fmaf(sc, (float)(s + 1), mind);
}

__global__ __launch_bounds__(256, 6) void pm_fused(
    const float* __restrict__ left,
    const float* __restrict__ right,
    const float* __restrict__ min_disp,
    const float* __restrict__ max_disp,
    const float* __restrict__ noise_in,
    float* __restrict__ nbuf0,
    float* __restrict__ nbuf1,
    float* __restrict__ disp_out)
{
    __shared__ unsigned int sP[C2 * PP];   // 16.9 KB
    __shared__ float sN[NPITCH];           // 1.0 KB

    const int w = threadIdx.x;
    const int h = blockIdx.x;              // fastest -> XCD locality
    const int s = blockIdx.y;
    const int row = h * W;

    float la[C], sc, imin;
    stage_block(left, right, min_disp, max_disp, sP, w, row, la, sc, imin, s);
    if (w < 2) sN[w * (NPITCH - 1)] = 0.0f;   // indices 0 and 257 stay zero
    __syncthreads();

    cg::grid_group grid = cg::this_grid();

    float np[3], ds, dn;

    // ---- round 0: horizontal, noise_in -> nbuf0 ----
    #pragma unroll
    for (int c = 0; c < 3; ++c) {
        const int x = w + c - 1;
        np[c] = (x >= 0 && x < W) ? noise_in[s * HW + row + x] : 0.0f;
    }
    eval_sample(sP, la, w, imin, sc, np, ds, dn);
    nbuf0[s * HW + row + w] = dn;

    grid.sync();

    // ---- round 1: vertical, nbuf0 -> sN (LDS only) ----
    #pragma unroll
    for (int c = 0; c < 3; ++c) {
        const int y = h + c - 1;
        np[c] = (y >= 0 && y < H) ? nbuf0[s * HW + y * W + w] : 0.0f;
    }
    eval_sample(sP, la, w, imin, sc, np, ds, dn);
    sN[1 + w] = dn;

    __syncthreads();

    // ---- round 2: horizontal, sN -> nbuf1 ----
    #pragma unroll
    for (int c = 0; c < 3; ++c)
        np[c] = sN[w + c];                 // pads give 0 at edges
    eval_sample(sP, la, w, imin, sc, np, ds, dn);
    nbuf1[s * HW + row + w] = dn;

    grid.sync();

    // ---- round 3: vertical, nbuf1 -> disp_out ----
    #pragma unroll
    for (int c = 0; c < 3; ++c) {
        const int y = h + c - 1;
        np[c] = (y >= 0 && y < H) ? nbuf1[s * HW + y * W + w] : 0.0f;
    }
    eval_sample(sP, la, w, imin, sc, np, ds, dn);
    disp_out[s * HW + row + w] = ds;
}

// ---------------- fallback: 3-kernel split (identical math) ----------------
// PHASE 0: round 0 (horizontal, global noise) -> nout
// PHASE 1: round 1 (vertical, nin) -> LDS -> round 2 (horizontal) -> nout
// PHASE 2: round 3 (vertical, nin) -> disp (ds) -> nout
template <int PHASE>
__global__ __launch_bounds__(256, 6) void pm_part(
    const float* __restrict__ left,
    const float* __restrict__ right,
    const float* __restrict__ min_disp,
    const float* __restrict__ max_disp,
    const float* __restrict__ nin,
    float* __restrict__ nout)
{
    __shared__ unsigned int sP[C2 * PP];
    __shared__ float sN[NPITCH];

    const int w = threadIdx.x;
    const int h = blockIdx.x;
    const int s = blockIdx.y;
    const int row = h * W;

    float la[C], sc, imin;
    stage_block(left, right, min_disp, max_disp, sP, w, row, la, sc, imin, s);
    if (PHASE == 1 && w < 2) sN[w * (NPITCH - 1)] = 0.0f;
    __syncthreads();

    float np[3], ds, dn;
    #pragma unroll
    for (int c = 0; c < 3; ++c) {
        if (PHASE == 0) {
            const int x = w + c - 1;
            np[c] = (x >= 0 && x < W) ? nin[s * HW + row + x] : 0.0f;
        } else {
            const int y = h + c - 1;
            np[c] = (y >= 0 && y < H) ? nin[s * HW + y * W + w] : 0.0f;
        }
    }
    eval_sample(sP, la, w, imin, sc, np, ds, dn);

    if (PHASE == 1) {
        sN[1 + w] = dn;
        __syncthreads();
        #pragma unroll
        for (int c = 0; c < 3; ++c)
            np[c] = sN[w + c];
        eval_sample(sP, la, w, imin, sc, np, ds, dn);
        nout[s * HW + row + w] = dn;
    } else {
        nout[s * HW + row + w] = (PHASE == 2) ? ds : dn;
    }
}

extern "C" void kernel_launch(void* const* d_in, const int* in_sizes, int n_in,
                              void* d_out, int out_size, void* d_ws, size_t ws_size,
                              hipStream_t stream) {
    const float* left  = (const float*)d_in[0];
    const float* right = (const float*)d_in[1];
    const float* mind  = (const float*)d_in[2];
    const float* maxd  = (const float*)d_in[3];
    const float* noise = (const float*)d_in[4];
    float* out   = (float*)d_out;
    float* nbuf0 = (float*)d_ws;               // S*H*W floats = 1.5 MB
    float* nbuf1 = nbuf0 + S * HW;             // next 1.5 MB

    dim3 grid(H, S);     // 128 x 12 = 1536 blocks = 6/CU co-resident
    dim3 block(256);

    void* args[] = {
        (void*)&left, (void*)&right, (void*)&mind, (void*)&maxd,
        (void*)&noise, (void*)&nbuf0, (void*)&nbuf1, (void*)&out
    };
    hipError_t err = hipLaunchCooperativeKernel(
        (const void*)pm_fused, grid, block, args, 0, stream);
    if (err != hipSuccess) {
        (void)hipGetLastError();   // clear error state, use split path
        pm_part<0><<<grid, block, 0, stream>>>(left, right, mind, maxd, noise, nbuf0);
        pm_part<1><<<grid, block, 0, stream>>>(left, right, mind, maxd, nbuf0, nbuf1);
        pm_part<2><<<grid, block, 0, stream>>>(left, right, mind, maxd, nbuf1, out);
    }
}

// Round 6
// 355.663 us; speedup vs baseline: 1.7175x; 1.7175x over previous
//
#include <hip/hip_runtime.h>
#include <hip/hip_fp16.h>
#include <hip/hip_cooperative_groups.h>

namespace cg = cooperative_groups;

// PatchMatch stereo — MI355X (gfx950), fused cooperative version (R5).
// B=1, C=32, H=128, W=256, S=12, FILTER=3, TEMP=7, ITERATIONS=2
// Rounds h,v,h,v fused into ONE kernel, 2 grid.sync()s.
// R5: fix the R4 spill (launch_bounds(256,6) -> VGPR 40 -> la[] spilled to
// scratch -> 460MB HBM churn). Now launch_bounds(256,4) (cap 128, no spill);
// left column packed half2 + v_dot2_f32_f16 halves both la registers (32->16)
// and inner-loop VALU. Right row stays f16-packed in LDS (18.4KB). Coop grid
// 1536 (6/CU) launches because ACTUAL resources (~50 VGPR, 18.4KB) allow
// >=6 blocks/CU; checked 3-kernel fallback otherwise.

namespace {
constexpr int C = 32;
constexpr int H = 128;
constexpr int W = 256;
constexpr int S = 12;
constexpr int HW = H * W;
constexpr int C2 = C / 2;             // 16 packed channel-pair rows
constexpr int PP = 264;               // words/row: [0..3]=pad, [4..259]=x 0..255, [260..263]=pad
constexpr int NPITCH = W + 2;         // LDS noise row: 1 front, 1 back pad
constexpr float TEMP_OVER_C = 7.0f / 32.0f;
constexpr float INTERVAL = 1.0f / (S + 1);

typedef _Float16 v2h __attribute__((ext_vector_type(2)));
}

__device__ __forceinline__ float fdot2_acc(v2h a, v2h b, float c) {
#if defined(__has_builtin) && __has_builtin(__builtin_amdgcn_fdot2)
    return __builtin_amdgcn_fdot2(a, b, c, false);
#else
    return c + (float)a.x * (float)b.x + (float)a.y * (float)b.y;
#endif
}

__device__ __forceinline__ void eval_sample(
    const unsigned int* __restrict__ sP, const v2h la2[C2], int w,
    float imin, float sc, const float np[3], float& ds_out, float& dn_out)
{
    float cost[3], dsamp[3];
    #pragma unroll
    for (int c = 0; c < 3; ++c) {
        const float disp = fmaf(np[c], sc, imin);
        dsamp[c] = disp;
        const float xs = (float)w - disp;
        const float x0f = floorf(xs);
        const float frac = xs - x0f;
        const int x0 = (int)x0f;
        const float v0 = (x0 >= 0 && x0 < W) ? 1.0f : 0.0f;
        const float v1 = (x0 >= -1 && x0 < W - 1) ? 1.0f : 0.0f;
        const int base = x0 < -1 ? -1 : (x0 > W - 1 ? W - 1 : x0);

        const unsigned int* p = &sP[4 + base];
        float d0 = 0.f, d1 = 0.f;
        #pragma unroll
        for (int k = 0; k < C2; ++k) {
            const unsigned int u0 = p[0];
            const unsigned int u1 = p[1];              // -> ds_read2_b32
            const v2h h0 = __builtin_bit_cast(v2h, u0); // (ch 2k, 2k+1) @ x0
            const v2h h1 = __builtin_bit_cast(v2h, u1); // same @ x0+1
            d0 = fdot2_acc(la2[k], h0, d0);
            d1 = fdot2_acc(la2[k], h1, d1);
            p += PP;
        }
        const float w0 = (1.0f - frac) * v0;
        const float w1 = frac * v1;
        cost[c] = (w0 * d0 + w1 * d1) * TEMP_OVER_C;
    }
    const float m = fmaxf(cost[0], fmaxf(cost[1], cost[2]));
    const float e0 = __expf(cost[0] - m);
    const float e1 = __expf(cost[1] - m);
    const float e2 = __expf(cost[2] - m);
    const float inv = 1.0f / (e0 + e1 + e2);
    ds_out = (e0 * dsamp[0] + e1 * dsamp[1] + e2 * dsamp[2]) * inv;
    dn_out = (e0 * np[0] + e1 * np[1] + e2 * np[2]) * inv;
}

// Stage right row (channel-pair packed f16) into sP, left column into la2.
__device__ __forceinline__ void stage_block(
    const float* __restrict__ left, const float* __restrict__ right,
    const float* __restrict__ min_disp, const float* __restrict__ max_disp,
    unsigned int* sP, int w, int row, v2h la2[C2], float& sc, float& imin, int s)
{
    // zero pads: 8 words per c2-row x 16 rows = 128 -> threads 0..127
    if (w < 128) {
        const int r = w >> 3;
        const int j = w & 7;
        const int idx = (j < 4) ? j : (256 + j);   // 0..3 or 260..263
        sP[r * PP + idx] = 0u;
    }
    // main words x=0..255 at [4..259]: 16 rows x 64 groups of 4 words
    #pragma unroll
    for (int i = 0; i < 4; ++i) {
        const int g = w + 256 * i;                 // group 0..1023
        const int c2 = g >> 6;
        const int x = (g & 63) << 2;
        const float4 a = *(const float4*)&right[(2 * c2)     * HW + row + x];
        const float4 b = *(const float4*)&right[(2 * c2 + 1) * HW + row + x];
        const v2h h0 = {(_Float16)a.x, (_Float16)b.x};
        const v2h h1 = {(_Float16)a.y, (_Float16)b.y};
        const v2h h2 = {(_Float16)a.z, (_Float16)b.z};
        const v2h h3 = {(_Float16)a.w, (_Float16)b.w};
        uint4 pk;
        pk.x = __builtin_bit_cast(unsigned int, h0);
        pk.y = __builtin_bit_cast(unsigned int, h1);
        pk.z = __builtin_bit_cast(unsigned int, h2);
        pk.w = __builtin_bit_cast(unsigned int, h3);
        *(uint4*)&sP[c2 * PP + 4 + x] = pk;        // 16B aligned
    }
    #pragma unroll
    for (int k = 0; k < C2; ++k) {
        const float l0 = left[(2 * k)     * HW + row + w];
        const float l1 = left[(2 * k + 1) * HW + row + w];
        la2[k] = {(_Float16)l0, (_Float16)l1};
    }

    const float mind = fmaxf(min_disp[row + w], 0.0f);
    const float maxd = fmaxf(max_disp[row + w], 0.0f);
    sc = (maxd - mind) * INTERVAL;
    imin = fmaf(sc, (float)(s + 1), mind);
}

__global__ __launch_bounds__(256, 4) void pm_fused(
    const float* __restrict__ left,
    const float* __restrict__ right,
    const float* __restrict__ min_disp,
    const float* __restrict__ max_disp,
    const float* __restrict__ noise_in,
    float* __restrict__ nbuf0,
    float* __restrict__ nbuf1,
    float* __restrict__ disp_out)
{
    __shared__ unsigned int sP[C2 * PP];   // 16.9 KB
    __shared__ float sN[NPITCH];           // 1.0 KB

    const int w = threadIdx.x;
    const int h = blockIdx.x;              // fastest -> XCD locality
    const int s = blockIdx.y;
    const int row = h * W;

    v2h la2[C2];
    float sc, imin;
    stage_block(left, right, min_disp, max_disp, sP, w, row, la2, sc, imin, s);
    if (w < 2) sN[w * (NPITCH - 1)] = 0.0f;   // indices 0 and 257 stay zero
    __syncthreads();

    cg::grid_group grid = cg::this_grid();

    float np[3], ds, dn;

    // ---- round 0: horizontal, noise_in -> nbuf0 ----
    #pragma unroll
    for (int c = 0; c < 3; ++c) {
        const int x = w + c - 1;
        np[c] = (x >= 0 && x < W) ? noise_in[s * HW + row + x] : 0.0f;
    }
    eval_sample(sP, la2, w, imin, sc, np, ds, dn);
    nbuf0[s * HW + row + w] = dn;

    grid.sync();

    // ---- round 1: vertical, nbuf0 -> sN (LDS only) ----
    #pragma unroll
    for (int c = 0; c < 3; ++c) {
        const int y = h + c - 1;
        np[c] = (y >= 0 && y < H) ? nbuf0[s * HW + y * W + w] : 0.0f;
    }
    eval_sample(sP, la2, w, imin, sc, np, ds, dn);
    sN[1 + w] = dn;

    __syncthreads();

    // ---- round 2: horizontal, sN -> nbuf1 ----
    #pragma unroll
    for (int c = 0; c < 3; ++c)
        np[c] = sN[w + c];                 // pads give 0 at edges
    eval_sample(sP, la2, w, imin, sc, np, ds, dn);
    nbuf1[s * HW + row + w] = dn;

    grid.sync();

    // ---- round 3: vertical, nbuf1 -> disp_out ----
    #pragma unroll
    for (int c = 0; c < 3; ++c) {
        const int y = h + c - 1;
        np[c] = (y >= 0 && y < H) ? nbuf1[s * HW + y * W + w] : 0.0f;
    }
    eval_sample(sP, la2, w, imin, sc, np, ds, dn);
    disp_out[s * HW + row + w] = ds;
}

// ---------------- fallback: 3-kernel split (identical math) ----------------
// PHASE 0: round 0 (horizontal, global noise) -> nout
// PHASE 1: round 1 (vertical, nin) -> LDS -> round 2 (horizontal) -> nout
// PHASE 2: round 3 (vertical, nin) -> disp (ds) -> nout
template <int PHASE>
__global__ __launch_bounds__(256, 4) void pm_part(
    const float* __restrict__ left,
    const float* __restrict__ right,
    const float* __restrict__ min_disp,
    const float* __restrict__ max_disp,
    const float* __restrict__ nin,
    float* __restrict__ nout)
{
    __shared__ unsigned int sP[C2 * PP];
    __shared__ float sN[NPITCH];

    const int w = threadIdx.x;
    const int h = blockIdx.x;
    const int s = blockIdx.y;
    const int row = h * W;

    v2h la2[C2];
    float sc, imin;
    stage_block(left, right, min_disp, max_disp, sP, w, row, la2, sc, imin, s);
    if (PHASE == 1 && w < 2) sN[w * (NPITCH - 1)] = 0.0f;
    __syncthreads();

    float np[3], ds, dn;
    #pragma unroll
    for (int c = 0; c < 3; ++c) {
        if (PHASE == 0) {
            const int x = w + c - 1;
            np[c] = (x >= 0 && x < W) ? nin[s * HW + row + x] : 0.0f;
        } else {
            const int y = h + c - 1;
            np[c] = (y >= 0 && y < H) ? nin[s * HW + y * W + w] : 0.0f;
        }
    }
    eval_sample(sP, la2, w, imin, sc, np, ds, dn);

    if (PHASE == 1) {
        sN[1 + w] = dn;
        __syncthreads();
        #pragma unroll
        for (int c = 0; c < 3; ++c)
            np[c] = sN[w + c];
        eval_sample(sP, la2, w, imin, sc, np, ds, dn);
        nout[s * HW + row + w] = dn;
    } else {
        nout[s * HW + row + w] = (PHASE == 2) ? ds : dn;
    }
}

extern "C" void kernel_launch(void* const* d_in, const int* in_sizes, int n_in,
                              void* d_out, int out_size, void* d_ws, size_t ws_size,
                              hipStream_t stream) {
    const float* left  = (const float*)d_in[0];
    const float* right = (const float*)d_in[1];
    const float* mind  = (const float*)d_in[2];
    const float* maxd  = (const float*)d_in[3];
    const float* noise = (const float*)d_in[4];
    float* out   = (float*)d_out;
    float* nbuf0 = (float*)d_ws;               // S*H*W floats = 1.5 MB
    float* nbuf1 = nbuf0 + S * HW;             // next 1.5 MB

    dim3 grid(H, S);     // 128 x 12 = 1536 blocks; needs 6/CU co-resident
    dim3 block(256);

    void* args[] = {
        (void*)&left, (void*)&right, (void*)&mind, (void*)&maxd,
        (void*)&noise, (void*)&nbuf0, (void*)&nbuf1, (void*)&out
    };
    hipError_t err = hipLaunchCooperativeKernel(
        (const void*)pm_fused, grid, block, args, 0, stream);
    if (err != hipSuccess) {
        (void)hipGetLastError();   // clear error state, use split path
        pm_part<0><<<grid, block, 0, stream>>>(left, right, mind, maxd, noise, nbuf0);
        pm_part<1><<<grid, block, 0, stream>>>(left, right, mind, maxd, nbuf0, nbuf1);
        pm_part<2><<<grid, block, 0, stream>>>(left, right, mind, maxd, nbuf1, out);
    }
}

// Round 7
// 236.538 us; speedup vs baseline: 2.5824x; 1.5036x over previous
//
#include <hip/hip_runtime.h>
#include <hip/hip_fp16.h>
#include <hip/hip_cooperative_groups.h>

namespace cg = cooperative_groups;

// PatchMatch stereo — MI355X (gfx950), fused cooperative version (R6).
// B=1, C=32, H=128, W=256, S=12, FILTER=3, TEMP=7, ITERATIONS=2
// Rounds h,v,h,v fused into ONE kernel, 2 grid.sync()s.
// R6: R5 regressed because launch_bounds squeezed VGPRs to 36 -> no
// memory-level parallelism -> serial LDS latency. Now: two-phase eval
// (batch all 16 ds_read2_b32 into a register array, then 4 independent
// fdot2 chains), launch_bounds(256,3) (VGPR cap 170). Grid 768 blocks
// (128 rows x 6 s-pairs) needs only 3 blocks/CU -> coop co-residency is
// guaranteed even at the VGPR cap. Checked 3-kernel fallback retained.

namespace {
constexpr int C = 32;
constexpr int H = 128;
constexpr int W = 256;
constexpr int S = 12;
constexpr int SG = 2;                 // s-groups per block
constexpr int GY = S / SG;            // 6
constexpr int HW = H * W;
constexpr int C2 = C / 2;             // 16 packed channel-pair rows
constexpr int PP = 264;               // words/row: [0..3]=pad, [4..259]=x 0..255, [260..263]=pad
constexpr int NPITCH = W + 2;         // LDS noise row: 1 front, 1 back pad
constexpr float TEMP_OVER_C = 7.0f / 32.0f;
constexpr float INTERVAL = 1.0f / (S + 1);

typedef _Float16 v2h __attribute__((ext_vector_type(2)));
}

__device__ __forceinline__ float fdot2_acc(v2h a, v2h b, float c) {
#if defined(__has_builtin) && __has_builtin(__builtin_amdgcn_fdot2)
    return __builtin_amdgcn_fdot2(a, b, c, false);
#else
    return c + (float)a.x * (float)b.x + (float)a.y * (float)b.y;
#endif
}

__device__ __forceinline__ void eval_sample(
    const unsigned int* __restrict__ sP, const v2h la2[C2], int w,
    float imin, float sc, const float np[3], float& ds_out, float& dn_out)
{
    float cost[3], dsamp[3];
    #pragma unroll
    for (int c = 0; c < 3; ++c) {
        const float disp = fmaf(np[c], sc, imin);
        dsamp[c] = disp;
        const float xs = (float)w - disp;
        const float x0f = floorf(xs);
        const float frac = xs - x0f;
        const int x0 = (int)x0f;
        const float v0 = (x0 >= 0 && x0 < W) ? 1.0f : 0.0f;
        const float v1 = (x0 >= -1 && x0 < W - 1) ? 1.0f : 0.0f;
        const int base = x0 < -1 ? -1 : (x0 > W - 1 ? W - 1 : x0);

        // phase 1: batch ALL channel-pair loads (16 ds_read2_b32 in flight)
        uint2 u[C2];
        {
            const unsigned int* p = &sP[4 + base];
            #pragma unroll
            for (int k = 0; k < C2; ++k) {
                u[k].x = p[0];
                u[k].y = p[1];          // adjacent -> ds_read2_b32
                p += PP;
            }
        }
        // phase 2: 4 independent dot chains (k even/odd x x0/x1)
        float d0e = 0.f, d0o = 0.f, d1e = 0.f, d1o = 0.f;
        #pragma unroll
        for (int k = 0; k < C2; k += 2) {
            d0e = fdot2_acc(la2[k],     __builtin_bit_cast(v2h, u[k].x),     d0e);
            d1e = fdot2_acc(la2[k],     __builtin_bit_cast(v2h, u[k].y),     d1e);
            d0o = fdot2_acc(la2[k + 1], __builtin_bit_cast(v2h, u[k + 1].x), d0o);
            d1o = fdot2_acc(la2[k + 1], __builtin_bit_cast(v2h, u[k + 1].y), d1o);
        }
        const float w0 = (1.0f - frac) * v0;
        const float w1 = frac * v1;
        cost[c] = (w0 * (d0e + d0o) + w1 * (d1e + d1o)) * TEMP_OVER_C;
    }
    const float m = fmaxf(cost[0], fmaxf(cost[1], cost[2]));
    const float e0 = __expf(cost[0] - m);
    const float e1 = __expf(cost[1] - m);
    const float e2 = __expf(cost[2] - m);
    const float inv = 1.0f / (e0 + e1 + e2);
    ds_out = (e0 * dsamp[0] + e1 * dsamp[1] + e2 * dsamp[2]) * inv;
    dn_out = (e0 * np[0] + e1 * np[1] + e2 * np[2]) * inv;
}

// Stage right row (channel-pair packed f16) into sP, left column into la2.
__device__ __forceinline__ void stage_block(
    const float* __restrict__ left, const float* __restrict__ right,
    const float* __restrict__ min_disp, const float* __restrict__ max_disp,
    unsigned int* sP, int w, int row, v2h la2[C2], float& sc, float imin[SG], int s0)
{
    // zero pads: 8 words per c2-row x 16 rows = 128 -> threads 0..127
    if (w < 128) {
        const int r = w >> 3;
        const int j = w & 7;
        const int idx = (j < 4) ? j : (256 + j);   // 0..3 or 260..263
        sP[r * PP + idx] = 0u;
    }
    // main words x=0..255 at [4..259]: 16 rows x 64 groups of 4 words
    #pragma unroll
    for (int i = 0; i < 4; ++i) {
        const int g = w + 256 * i;                 // group 0..1023
        const int c2 = g >> 6;
        const int x = (g & 63) << 2;
        const float4 a = *(const float4*)&right[(2 * c2)     * HW + row + x];
        const float4 b = *(const float4*)&right[(2 * c2 + 1) * HW + row + x];
        const v2h h0 = {(_Float16)a.x, (_Float16)b.x};
        const v2h h1 = {(_Float16)a.y, (_Float16)b.y};
        const v2h h2 = {(_Float16)a.z, (_Float16)b.z};
        const v2h h3 = {(_Float16)a.w, (_Float16)b.w};
        uint4 pk;
        pk.x = __builtin_bit_cast(unsigned int, h0);
        pk.y = __builtin_bit_cast(unsigned int, h1);
        pk.z = __builtin_bit_cast(unsigned int, h2);
        pk.w = __builtin_bit_cast(unsigned int, h3);
        *(uint4*)&sP[c2 * PP + 4 + x] = pk;        // 16B aligned
    }
    #pragma unroll
    for (int k = 0; k < C2; ++k) {
        const float l0 = left[(2 * k)     * HW + row + w];
        const float l1 = left[(2 * k + 1) * HW + row + w];
        la2[k] = {(_Float16)l0, (_Float16)l1};
    }

    const float mind = fmaxf(min_disp[row + w], 0.0f);
    const float maxd = fmaxf(max_disp[row + w], 0.0f);
    sc = (maxd - mind) * INTERVAL;
    #pragma unroll
    for (int si = 0; si < SG; ++si)
        imin[si] = fmaf(sc, (float)(s0 + si + 1), mind);
}

__global__ __launch_bounds__(256, 3) void pm_fused(
    const float* __restrict__ left,
    const float* __restrict__ right,
    const float* __restrict__ min_disp,
    const float* __restrict__ max_disp,
    const float* __restrict__ noise_in,
    float* __restrict__ nbuf0,
    float* __restrict__ nbuf1,
    float* __restrict__ disp_out)
{
    __shared__ unsigned int sP[C2 * PP];   // 16.9 KB
    __shared__ float sN[SG * NPITCH];      // 2.1 KB

    const int w  = threadIdx.x;
    const int h  = blockIdx.x;             // fastest -> XCD locality
    const int s0 = SG * blockIdx.y;
    const int row = h * W;

    v2h la2[C2];
    float sc, imin[SG];
    stage_block(left, right, min_disp, max_disp, sP, w, row, la2, sc, imin, s0);
    if (w < 2 * SG)                        // edge pads stay zero
        sN[(w >> 1) * NPITCH + (w & 1) * (NPITCH - 1)] = 0.0f;
    __syncthreads();

    cg::grid_group grid = cg::this_grid();

    float np[3], ds, dn;

    // ---- round 0: horizontal, noise_in -> nbuf0 ----
    #pragma unroll 1
    for (int si = 0; si < SG; ++si) {
        const int s = s0 + si;
        #pragma unroll
        for (int c = 0; c < 3; ++c) {
            const int x = w + c - 1;
            np[c] = (x >= 0 && x < W) ? noise_in[s * HW + row + x] : 0.0f;
        }
        eval_sample(sP, la2, w, imin[si], sc, np, ds, dn);
        nbuf0[s * HW + row + w] = dn;
    }

    grid.sync();

    // ---- round 1: vertical, nbuf0 -> sN (LDS only) ----
    #pragma unroll 1
    for (int si = 0; si < SG; ++si) {
        const int s = s0 + si;
        #pragma unroll
        for (int c = 0; c < 3; ++c) {
            const int y = h + c - 1;
            np[c] = (y >= 0 && y < H) ? nbuf0[s * HW + y * W + w] : 0.0f;
        }
        eval_sample(sP, la2, w, imin[si], sc, np, ds, dn);
        sN[si * NPITCH + 1 + w] = dn;
    }

    __syncthreads();

    // ---- round 2: horizontal, sN -> nbuf1 ----
    #pragma unroll 1
    for (int si = 0; si < SG; ++si) {
        const int s = s0 + si;
        #pragma unroll
        for (int c = 0; c < 3; ++c)
            np[c] = sN[si * NPITCH + w + c];   // pads give 0 at edges
        eval_sample(sP, la2, w, imin[si], sc, np, ds, dn);
        nbuf1[s * HW + row + w] = dn;
    }

    grid.sync();

    // ---- round 3: vertical, nbuf1 -> disp_out ----
    #pragma unroll 1
    for (int si = 0; si < SG; ++si) {
        const int s = s0 + si;
        #pragma unroll
        for (int c = 0; c < 3; ++c) {
            const int y = h + c - 1;
            np[c] = (y >= 0 && y < H) ? nbuf1[s * HW + y * W + w] : 0.0f;
        }
        eval_sample(sP, la2, w, imin[si], sc, np, ds, dn);
        disp_out[s * HW + row + w] = ds;
    }
}

// ---------------- fallback: 3-kernel split (identical math) ----------------
// PHASE 0: round 0 (horizontal, global noise) -> nout
// PHASE 1: round 1 (vertical, nin) -> LDS -> round 2 (horizontal) -> nout
// PHASE 2: round 3 (vertical, nin) -> disp (ds) -> nout
template <int PHASE>
__global__ __launch_bounds__(256, 3) void pm_part(
    const float* __restrict__ left,
    const float* __restrict__ right,
    const float* __restrict__ min_disp,
    const float* __restrict__ max_disp,
    const float* __restrict__ nin,
    float* __restrict__ nout)
{
    __shared__ unsigned int sP[C2 * PP];
    __shared__ float sN[SG * NPITCH];

    const int w  = threadIdx.x;
    const int h  = blockIdx.x;
    const int s0 = SG * blockIdx.y;
    const int row = h * W;

    v2h la2[C2];
    float sc, imin[SG];
    stage_block(left, right, min_disp, max_disp, sP, w, row, la2, sc, imin, s0);
    if (PHASE == 1 && w < 2 * SG)
        sN[(w >> 1) * NPITCH + (w & 1) * (NPITCH - 1)] = 0.0f;
    __syncthreads();

    float np[3], ds, dn;
    #pragma unroll 1
    for (int si = 0; si < SG; ++si) {
        const int s = s0 + si;
        #pragma unroll
        for (int c = 0; c < 3; ++c) {
            if (PHASE == 0) {
                const int x = w + c - 1;
                np[c] = (x >= 0 && x < W) ? nin[s * HW + row + x] : 0.0f;
            } else {
                const int y = h + c - 1;
                np[c] = (y >= 0 && y < H) ? nin[s * HW + y * W + w] : 0.0f;
            }
        }
        eval_sample(sP, la2, w, imin[si], sc, np, ds, dn);
        if (PHASE == 1) sN[si * NPITCH + 1 + w] = dn;
        else            nout[s * HW + row + w] = (PHASE == 2) ? ds : dn;
    }

    if (PHASE == 1) {
        __syncthreads();
        #pragma unroll 1
        for (int si = 0; si < SG; ++si) {
            const int s = s0 + si;
            #pragma unroll
            for (int c = 0; c < 3; ++c)
                np[c] = sN[si * NPITCH + w + c];
            eval_sample(sP, la2, w, imin[si], sc, np, ds, dn);
            nout[s * HW + row + w] = dn;
        }
    }
}

extern "C" void kernel_launch(void* const* d_in, const int* in_sizes, int n_in,
                              void* d_out, int out_size, void* d_ws, size_t ws_size,
                              hipStream_t stream) {
    const float* left  = (const float*)d_in[0];
    const float* right = (const float*)d_in[1];
    const float* mind  = (const float*)d_in[2];
    const float* maxd  = (const float*)d_in[3];
    const float* noise = (const float*)d_in[4];
    float* out   = (float*)d_out;
    float* nbuf0 = (float*)d_ws;               // S*H*W floats = 1.5 MB
    float* nbuf1 = nbuf0 + S * HW;             // next 1.5 MB

    dim3 grid(H, GY);    // 128 x 6 = 768 blocks; 3 blocks/CU guaranteed
    dim3 block(256);

    void* args[] = {
        (void*)&left, (void*)&right, (void*)&mind, (void*)&maxd,
        (void*)&noise, (void*)&nbuf0, (void*)&nbuf1, (void*)&out
    };
    hipError_t err = hipLaunchCooperativeKernel(
        (const void*)pm_fused, grid, block, args, 0, stream);
    if (err != hipSuccess) {
        (void)hipGetLastError();   // clear error state, use split path
        pm_part<0><<<grid, block, 0, stream>>>(left, right, mind, maxd, noise, nbuf0);
        pm_part<1><<<grid, block, 0, stream>>>(left, right, mind, maxd, nbuf0, nbuf1);
        pm_part<2><<<grid, block, 0, stream>>>(left, right, mind, maxd, nbuf1, out);
    }
}